// Round 25
// baseline (2054.769 us; speedup 1.0000x reference)
//
#include <hip/hip_runtime.h>
#include <hip/hip_bf16.h>

typedef __attribute__((ext_vector_type(8))) short bf16x8;
typedef __attribute__((ext_vector_type(4))) float f32x4;
typedef __attribute__((ext_vector_type(4))) unsigned int u32x4;

#define BB 32
#define SS 512
#define DD 512
#define HH 1024
#define KTOT (DD + HH)      // 1536
#define NCH 8               // h-columns per block
#define NCOL 32             // 4 gates x 8 cols
#define NBLK 256
#define GBLK 128            // blocks per group
#define NB2 16              // batches per group
#define HW2 (HH / 2)        // h row in packed u32 (2 bf16 each)
#define LROW 516            // htile row stride in u32 (2064 B)

// Cross-block state: zero-initialized device globals, self-reset each run.
__device__ unsigned int g_flag[NBLK * 16];        // per-block step flag, 64B-padded
__device__ unsigned int g_done;                   // end-of-run reset rendezvous
__device__ unsigned int g_hws[2 * BB * HW2];      // bf16-pair h ping-pong

struct Params {
    const float* x;        // [B][S][D] fp32
    const float* Wi[4];    // [D][H]
    const float* Wh[4];    // [H][H]
    const float* bias[4];  // [H]
    float* out_h;          // [B][S][H] fp32
    float* out_c;          // [B][S][H] fp32
};

static __device__ __forceinline__ short f2bf(float f) {
    __hip_bfloat16 h = __float2bfloat16(f);
    return *reinterpret_cast<short*>(&h);
}

__launch_bounds__(256, 1)
__global__ void lstm_mfma(Params p) {
    // Fragment-major B: Wb[k8][col][8] -> 16 consecutive cols read 16
    // consecutive 16B fragments (conflict-free ds_read_b128). Proven r9-r24.
    __shared__ short Wb[(KTOT / 8) * NCOL * 8];   // 96 KB
    __shared__ __align__(16) unsigned htile[NB2 * LROW];  // 33 KB h tile (dedup)
    __shared__ float accl[2][NB2][NCOL];          // [k-half][batch][gate-col]
    __shared__ float c_st[NB2][NCH];              // fp32 cell state
    __shared__ float bias_l[NCOL];
    __shared__ unsigned psync[2];         // per-kh monotone step counters

    const int tid = threadIdx.x;
    const int blk = blockIdx.x;
    const int gid = blk & 1;              // batch group
    const int lid = blk >> 1;             // 0..127 within group
    const int bb0 = gid * NB2;            // first batch row
    const int hc0 = lid * NCH;            // first h column

    if (tid == 0) { psync[0] = 0u; psync[1] = 0u; }

    // ---- stage weights to LDS once (coalesced f32x4 rows) ----
    for (int idx = tid; idx < KTOT * 8; idx += 256) {
        const int r = idx >> 3, q = idx & 7;
        const int g = q >> 1, half = (q & 1) * 4;
        f32x4 w = (r < DD)
            ? *(const f32x4*)&p.Wi[g][(size_t)r * HH + hc0 + half]
            : *(const f32x4*)&p.Wh[g][(size_t)(r - DD) * HH + hc0 + half];
        #pragma unroll
        for (int jj = 0; jj < 4; ++jj)
            Wb[(((r >> 3) * NCOL + g * 8 + half + jj) << 3) + (r & 7)] = f2bf(w[jj]);
    }
    if (tid < NCOL) bias_l[tid] = p.bias[tid >> 3][hc0 + (tid & 7)];
    __syncthreads();

    const int wave = tid >> 6;
    const int lane = tid & 63;
    const int ct  = wave & 1;               // col-tile (16 gate-cols each)
    const int kh  = wave >> 1;              // K half
    const int arow = bb0 + (lane & 15);     // global batch row for A (x-part)
    const int gc  = ct * 16 + (lane & 15);  // gate-col for B
    const int kg  = lane >> 4;              // k-subgroup 0..3
    const int kgb = kg * 8;

    // LDS fragment bases (bf16x8-aligned, conflict-free)
    const short* xB = &Wb[(((kh * 32 + kg) * NCOL + gc) << 3)];
    const short* hB = &Wb[(((64 + kh * 64 + kg) * NCOL + gc) << 3)];
    // A-fragment base in htile: row = lane&15, k half + subgroup offset
    const short* hA = (const short*)htile + (lane & 15) * (LROW * 2) + kh * 512 + kgb;

    // per-wave quarter geometry: this wave gates+loads quarter kh*2+ct
    const int qrt  = kh * 2 + ct;           // 0..3 (32 producers, 8 KB each)
    const int qrow = lane >> 2;             // 0..15
    const int qseg = lane & 3;              // 0..3
    // this wave's gate: its quarter's 32 flags, 1 per 2 lanes
    const unsigned* fptr = &g_flag[(gid * GBLK + qrt * 32 + (lane & 31)) << 4];

    // x-part for one step (8 chunks/wave: k = kh*256 + cx*32 + kg*8)
    auto xpart = [&](int t, f32x4 a_cc) -> f32x4 {
        const float* xrow = p.x + ((size_t)arow * SS + t) * DD;
        #pragma unroll 4
        for (int cx = 0; cx < 8; ++cx) {
            const int k0 = kh * 256 + cx * 32 + kgb;
            f32x4 a0 = *(const f32x4*)(xrow + k0);
            f32x4 a1 = *(const f32x4*)(xrow + k0 + 4);
            bf16x8 a;
            a[0] = f2bf(a0[0]); a[1] = f2bf(a0[1]);
            a[2] = f2bf(a0[2]); a[3] = f2bf(a0[3]);
            a[4] = f2bf(a1[0]); a[5] = f2bf(a1[1]);
            a[6] = f2bf(a1[2]); a[7] = f2bf(a1[3]);
            a_cc = __builtin_amdgcn_mfma_f32_16x16x32_bf16(
                a, *(const bf16x8*)(xB + (size_t)cx * 1024), a_cc, 0, 0, 0);
        }
        return a_cc;
    };

    f32x4 acc = {0.f, 0.f, 0.f, 0.f};
    acc = xpart(0, acc);                   // prologue: x-part of t=0

    for (int t = 0; t < SS; ++t) {
        if (t > 0) {
            // ---- gate: 2-deep pipelined poll of THIS quarter's 32 flags ----
            unsigned fA = 0, fB = 0;
            {
                asm volatile("global_load_dword %0, %2, off sc0 sc1\n\t"
                             "global_load_dword %1, %2, off sc0 sc1"
                             : "=&v"(fA), "=&v"(fB) : "v"(fptr));
                unsigned it = 0;
                for (;;) {
                    asm volatile("s_waitcnt vmcnt(1)" ::: "memory");
                    __builtin_amdgcn_sched_barrier(0);
                    if (__all(fA >= (unsigned)t)) break;
                    asm volatile("global_load_dword %0, %1, off sc0 sc1"
                                 : "=v"(fA) : "v"(fptr));
                    asm volatile("s_waitcnt vmcnt(1)" ::: "memory");
                    __builtin_amdgcn_sched_barrier(0);
                    if (__all(fB >= (unsigned)t)) break;
                    asm volatile("global_load_dword %0, %1, off sc0 sc1"
                                 : "=v"(fB) : "v"(fptr));
                    if ((++it & 7) == 7) __builtin_amdgcn_s_sleep(1);
                    if (it > (1u << 19)) break;   // fail loud, not hang
                }
            }
            asm volatile("" ::: "memory");

            // ---- wave coop load: this quarter's 8 KB -> htile quarter ----
            {
                const unsigned* src = g_hws + ((t - 1) & 1) * (BB * HW2)
                                    + (size_t)(bb0 + qrow) * HW2
                                    + kh * 256 + ct * 128 + qseg * 4;
                u32x4 v0, v1, v2, v3, v4, v5, v6, v7;
#define LDH(dst, OFF) asm volatile("global_load_dwordx4 %0, %1, off offset:" OFF " sc0 sc1" \
                                   : "=v"(dst) : "v"(src))
                LDH(v0, "0");   LDH(v1, "64");  LDH(v2, "128"); LDH(v3, "192");
                LDH(v4, "256"); LDH(v5, "320"); LDH(v6, "384"); LDH(v7, "448");
#undef LDH
                asm volatile("s_waitcnt vmcnt(0)" ::: "memory");
                __builtin_amdgcn_sched_barrier(0);
                // keep poll regs live past the drain
                asm volatile("" :: "v"(fA), "v"(fB));
                unsigned* dst = &htile[qrow * LROW + kh * 256 + ct * 128 + qseg * 4];
                *(u32x4*)(dst)       = v0; *(u32x4*)(dst + 16)  = v1;
                *(u32x4*)(dst + 32)  = v2; *(u32x4*)(dst + 48)  = v3;
                *(u32x4*)(dst + 64)  = v4; *(u32x4*)(dst + 80)  = v5;
                *(u32x4*)(dst + 96)  = v6; *(u32x4*)(dst + 112) = v7;
            }
            // own-quarter writes visible to own wave; signal partner
            asm volatile("s_waitcnt lgkmcnt(0)" ::: "memory");
            if (lane == 0)
                __hip_atomic_fetch_add(&psync[kh], 1u, __ATOMIC_RELEASE,
                                       __HIP_MEMORY_SCOPE_WORKGROUP);

            // ---- FMH own quarter (8 chunks) while partner gates/loads ----
#define FMH(CH) { bf16x8 av = *(const bf16x8*)(hA + (CH) * 32);                \
        acc = __builtin_amdgcn_mfma_f32_16x16x32_bf16(                         \
            av, *(const bf16x8*)(hB + (CH) * 1024), acc, 0, 0, 0); }
            if (ct == 0) {
                FMH(0)  FMH(1)  FMH(2)  FMH(3)
                FMH(4)  FMH(5)  FMH(6)  FMH(7)
            } else {
                FMH(8)  FMH(9)  FMH(10) FMH(11)
                FMH(12) FMH(13) FMH(14) FMH(15)
            }
            // ---- wait: partner quarter written, then its 8 chunks ----
            {
                unsigned it = 0;
                while (__hip_atomic_load(&psync[kh], __ATOMIC_ACQUIRE,
                                         __HIP_MEMORY_SCOPE_WORKGROUP)
                       < 2u * (unsigned)t) {
                    if (++it > (1u << 22)) break;   // fail loud, not hang
                }
            }
            __builtin_amdgcn_sched_barrier(0);
            if (ct == 0) {
                FMH(8)  FMH(9)  FMH(10) FMH(11)
                FMH(12) FMH(13) FMH(14) FMH(15)
            } else {
                FMH(0)  FMH(1)  FMH(2)  FMH(3)
                FMH(4)  FMH(5)  FMH(6)  FMH(7)
            }
#undef FMH
        }
        #pragma unroll
        for (int i = 0; i < 4; ++i)
            accl[kh][(lane >> 4) * 4 + i][gc] = acc[i];
        __syncthreads();   // all FMH reads done; accl complete for gating

        if (tid < 64) {                    // gating: lane -> (batch, col-pair)
            const int b = lane >> 2, jp = (lane & 3) * 2;
            float hn2[2], cn2[2];
            #pragma unroll
            for (int u = 0; u < 2; ++u) {
                const int j = jp + u;
                float pre[4];
                #pragma unroll
                for (int g = 0; g < 4; ++g) {
                    const int c = g * 8 + j;
                    pre[g] = accl[0][b][c] + accl[1][b][c] + bias_l[c];
                }
                const float ig = 1.f / (1.f + __expf(-pre[0]));
                const float fg = 1.f / (1.f + __expf(-pre[1]));
                const float gg = tanhf(pre[2]);
                const float og = 1.f / (1.f + __expf(-pre[3]));
                const float cp = (t == 0) ? 0.f : c_st[b][j];
                const float cn = fg * cp + ig * gg;
                const float hn = og * tanhf(cn);
                c_st[b][j] = cn;
                hn2[u] = hn; cn2[u] = cn;
            }
            const unsigned pack = (unsigned)(unsigned short)f2bf(hn2[0])
                                | ((unsigned)(unsigned short)f2bf(hn2[1]) << 16);
            __hip_atomic_store(
                &g_hws[(t & 1) * (BB * HW2) + (bb0 + b) * HW2 + ((hc0 + jp) >> 1)],
                pack, __ATOMIC_RELAXED, __HIP_MEMORY_SCOPE_AGENT);
            // wave-level ack: all lanes' h-stores reached the coherence point
            asm volatile("s_waitcnt vmcnt(0)" ::: "memory");
            if (lane == 0 && t < SS - 1)
                __hip_atomic_store(&g_flag[(gid * GBLK + lid) << 4], (unsigned)(t + 1),
                                   __ATOMIC_RELAXED, __HIP_MEMORY_SCOPE_AGENT);
            // fp32 outputs off the critical path, after the flag
            const size_t o = ((size_t)(bb0 + b) * SS + t) * HH + hc0 + jp;
            *(float2*)&p.out_h[o] = make_float2(hn2[0], hn2[1]);
            *(float2*)&p.out_c[o] = make_float2(cn2[0], cn2[1]);
        }
        if (t == SS - 1) break;
        // ---- hide flag propagation: x-part of t+1 (h-independent) ----
        acc = (f32x4){0.f, 0.f, 0.f, 0.f};
        acc = xpart(t + 1, acc);
    }

    // ---- end-of-run: last block resets flags for the next graph replay ----
    __syncthreads();
    if (tid == 0) {
        unsigned v = __hip_atomic_fetch_add(&g_done, 1u, __ATOMIC_RELAXED,
                                            __HIP_MEMORY_SCOPE_AGENT) + 1;
        if (v == NBLK) {
            for (int i = 0; i < NBLK; ++i)
                __hip_atomic_store(&g_flag[i << 4], 0u, __ATOMIC_RELAXED,
                                   __HIP_MEMORY_SCOPE_AGENT);
            __hip_atomic_store(&g_done, 0u, __ATOMIC_RELAXED,
                               __HIP_MEMORY_SCOPE_AGENT);
        }
    }
}

extern "C" void kernel_launch(void* const* d_in, const int* in_sizes, int n_in,
                              void* d_out, int out_size, void* d_ws, size_t ws_size,
                              hipStream_t stream) {
    (void)in_sizes; (void)n_in; (void)d_ws; (void)ws_size; (void)out_size;
    Params p;
    p.x = (const float*)d_in[0];
    for (int g = 0; g < 4; ++g) {
        p.Wi[g]   = (const float*)d_in[1 + g];
        p.Wh[g]   = (const float*)d_in[5 + g];
        p.bias[g] = (const float*)d_in[9 + g];
    }
    p.out_h = (float*)d_out;
    p.out_c = p.out_h + (size_t)BB * SS * HH;
    lstm_mfma<<<dim3(NBLK), dim3(256), 0, stream>>>(p);
}

// Round 26
// 1928.823 us; speedup vs baseline: 1.0653x; 1.0653x over previous
//
#include <hip/hip_runtime.h>
#include <hip/hip_bf16.h>

typedef __attribute__((ext_vector_type(8))) short bf16x8;
typedef __attribute__((ext_vector_type(4))) float f32x4;
typedef __attribute__((ext_vector_type(4))) unsigned int u32x4;

#define BB 32
#define SS 512
#define DD 512
#define HH 1024
#define KTOT (DD + HH)      // 1536
#define NCH 8               // h-columns per block
#define NCOL 32             // 4 gates x 8 cols
#define NBLK 256
#define GBLK 128            // blocks per group
#define NB2 16              // batches per group
#define HW2 (HH / 2)        // h row in packed u32 (2 bf16 each)
#define LROW 516            // htile row stride in u32 (2064 B)

// Cross-block state: zero-initialized device globals, self-reset each run.
__device__ unsigned int g_flag[NBLK * 16];        // per-block step flag, 64B-padded
__device__ unsigned int g_done;                   // end-of-run reset rendezvous
__device__ unsigned int g_hws[2 * BB * HW2];      // bf16-pair h ping-pong

struct Params {
    const float* x;        // [B][S][D] fp32
    const float* Wi[4];    // [D][H]
    const float* Wh[4];    // [H][H]
    const float* bias[4];  // [H]
    float* out_h;          // [B][S][H] fp32
    float* out_c;          // [B][S][H] fp32
};

static __device__ __forceinline__ short f2bf(float f) {
    __hip_bfloat16 h = __float2bfloat16(f);
    return *reinterpret_cast<short*>(&h);
}

__launch_bounds__(256, 1)
__global__ void lstm_mfma(Params p) {
    // Fragment-major B: Wb[k8][col][8] -> 16 consecutive cols read 16
    // consecutive 16B fragments (conflict-free ds_read_b128). Proven r9-r24.
    __shared__ short Wb[(KTOT / 8) * NCOL * 8];   // 96 KB
    __shared__ __align__(16) unsigned htile[NB2 * LROW];  // 33 KB h tile (dedup)
    __shared__ float accl[2][NB2][NCOL];          // [k-half][batch][gate-col]
    __shared__ float c_st[NB2][NCH];              // fp32 cell state
    __shared__ float bias_l[NCOL];
    __shared__ unsigned psync[2];         // per-pair monotone step counters

    const int tid = threadIdx.x;
    const int blk = blockIdx.x;
    const int gid = blk & 1;              // batch group
    const int lid = blk >> 1;             // 0..127 within group
    const int bb0 = gid * NB2;            // first batch row
    const int hc0 = lid * NCH;            // first h column

    if (tid == 0) { psync[0] = 0u; psync[1] = 0u; }

    // ---- stage weights to LDS once (coalesced f32x4 rows) ----
    for (int idx = tid; idx < KTOT * 8; idx += 256) {
        const int r = idx >> 3, q = idx & 7;
        const int g = q >> 1, half = (q & 1) * 4;
        f32x4 w = (r < DD)
            ? *(const f32x4*)&p.Wi[g][(size_t)r * HH + hc0 + half]
            : *(const f32x4*)&p.Wh[g][(size_t)(r - DD) * HH + hc0 + half];
        #pragma unroll
        for (int jj = 0; jj < 4; ++jj)
            Wb[(((r >> 3) * NCOL + g * 8 + half + jj) << 3) + (r & 7)] = f2bf(w[jj]);
    }
    if (tid < NCOL) bias_l[tid] = p.bias[tid >> 3][hc0 + (tid & 7)];
    __syncthreads();

    const int wave = tid >> 6;
    const int lane = tid & 63;
    const int ct  = wave & 1;               // col-tile (16 gate-cols each)
    const int kh  = wave >> 1;              // K half
    const int arow = bb0 + (lane & 15);     // global batch row for A (x-part)
    const int gc  = ct * 16 + (lane & 15);  // gate-col for B
    const int kg  = lane >> 4;              // k-subgroup 0..3
    const int kgb = kg * 8;

    // LDS fragment bases (bf16x8-aligned, conflict-free)
    const short* xB = &Wb[(((kh * 32 + kg) * NCOL + gc) << 3)];
    const short* hB = &Wb[(((64 + kh * 64 + kg) * NCOL + gc) << 3)];
    // A-fragment base in htile: row = lane&15, k half + subgroup offset
    const short* hA = (const short*)htile + (lane & 15) * (LROW * 2) + kh * 512 + kgb;

    // per-pair coop-load geometry: 128 threads cover this kh-half (16KB)
    const int pr   = tid & 127;             // index within pair
    const int prow = pr >> 3;               // 0..15
    const int pseg = pr & 7;                // 0..7
    // this wave's gate: 64 flags of its own half, 1 per lane
    const unsigned* fptr = &g_flag[(gid * GBLK + kh * 64 + lane) << 4];

    // x-part for one step (8 chunks/wave: k = kh*256 + cx*32 + kg*8)
    auto xpart = [&](int t, f32x4 a_cc) -> f32x4 {
        const float* xrow = p.x + ((size_t)arow * SS + t) * DD;
        #pragma unroll 4
        for (int cx = 0; cx < 8; ++cx) {
            const int k0 = kh * 256 + cx * 32 + kgb;
            f32x4 a0 = *(const f32x4*)(xrow + k0);
            f32x4 a1 = *(const f32x4*)(xrow + k0 + 4);
            bf16x8 a;
            a[0] = f2bf(a0[0]); a[1] = f2bf(a0[1]);
            a[2] = f2bf(a0[2]); a[3] = f2bf(a0[3]);
            a[4] = f2bf(a1[0]); a[5] = f2bf(a1[1]);
            a[6] = f2bf(a1[2]); a[7] = f2bf(a1[3]);
            a_cc = __builtin_amdgcn_mfma_f32_16x16x32_bf16(
                a, *(const bf16x8*)(xB + (size_t)cx * 1024), a_cc, 0, 0, 0);
        }
        return a_cc;
    };

    f32x4 acc = {0.f, 0.f, 0.f, 0.f};
    acc = xpart(0, acc);                   // prologue: x-part of t=0

    for (int t = 0; t < SS; ++t) {
        if (t > 0) {
            // ---- gate: 2-deep pipelined poll of THIS half's 64 flags ----
            unsigned fA = 0, fB = 0;
            {
                asm volatile("global_load_dword %0, %2, off sc0 sc1\n\t"
                             "global_load_dword %1, %2, off sc0 sc1"
                             : "=&v"(fA), "=&v"(fB) : "v"(fptr));
                unsigned it = 0;
                for (;;) {
                    asm volatile("s_waitcnt vmcnt(1)" ::: "memory");
                    __builtin_amdgcn_sched_barrier(0);
                    if (__all(fA >= (unsigned)t)) break;
                    asm volatile("global_load_dword %0, %1, off sc0 sc1"
                                 : "=v"(fA) : "v"(fptr));
                    asm volatile("s_waitcnt vmcnt(1)" ::: "memory");
                    __builtin_amdgcn_sched_barrier(0);
                    if (__all(fB >= (unsigned)t)) break;
                    asm volatile("global_load_dword %0, %1, off sc0 sc1"
                                 : "=v"(fB) : "v"(fptr));
                    if ((++it & 7) == 7) __builtin_amdgcn_s_sleep(1);
                    if (it > (1u << 19)) break;   // fail loud, not hang
                }
            }
            asm volatile("" ::: "memory");

            // ---- pair coop load: this half's 16 KB -> htile half ----
            {
                const unsigned* src = g_hws + ((t - 1) & 1) * (BB * HW2)
                                    + (size_t)(bb0 + prow) * HW2
                                    + kh * 256 + pseg * 4;
                u32x4 v0, v1, v2, v3, v4, v5, v6, v7;
#define LDH(dst, OFF) asm volatile("global_load_dwordx4 %0, %1, off offset:" OFF " sc0 sc1" \
                                   : "=v"(dst) : "v"(src))
                LDH(v0, "0");   LDH(v1, "128"); LDH(v2, "256"); LDH(v3, "384");
                LDH(v4, "512"); LDH(v5, "640"); LDH(v6, "768"); LDH(v7, "896");
#undef LDH
                asm volatile("s_waitcnt vmcnt(0)" ::: "memory");
                __builtin_amdgcn_sched_barrier(0);
                // keep poll regs live past the drain (leftover in-flight load
                // lands into its reserved reg; drained by the vmcnt(0) above)
                asm volatile("" :: "v"(fA), "v"(fB));
                unsigned* dst = &htile[prow * LROW + kh * 256 + pseg * 4];
                *(u32x4*)(dst)       = v0; *(u32x4*)(dst + 32)  = v1;
                *(u32x4*)(dst + 64)  = v2; *(u32x4*)(dst + 96)  = v3;
                *(u32x4*)(dst + 128) = v4; *(u32x4*)(dst + 160) = v5;
                *(u32x4*)(dst + 192) = v6; *(u32x4*)(dst + 224) = v7;
            }
            // ---- pair-internal sync: both waves' half-writes visible ----
            asm volatile("s_waitcnt lgkmcnt(0)" ::: "memory");
            if (lane == 0)
                __hip_atomic_fetch_add(&psync[kh], 1u, __ATOMIC_RELEASE,
                                       __HIP_MEMORY_SCOPE_WORKGROUP);
            {
                unsigned it = 0;
                while (__hip_atomic_load(&psync[kh], __ATOMIC_ACQUIRE,
                                         __HIP_MEMORY_SCOPE_WORKGROUP)
                       < 2u * (unsigned)t) {
                    if (++it > (1u << 22)) break;   // fail loud, not hang
                }
            }
            __builtin_amdgcn_sched_barrier(0);

            // ---- h-part: 16x (ds_read_b128 A from htile + ds B) ----
#define FMH(CH) { bf16x8 av = *(const bf16x8*)(hA + (CH) * 32);                \
        acc = __builtin_amdgcn_mfma_f32_16x16x32_bf16(                         \
            av, *(const bf16x8*)(hB + (CH) * 1024), acc, 0, 0, 0); }
            FMH(0)  FMH(1)  FMH(2)  FMH(3)
            FMH(4)  FMH(5)  FMH(6)  FMH(7)
            FMH(8)  FMH(9)  FMH(10) FMH(11)
            FMH(12) FMH(13) FMH(14) FMH(15)
#undef FMH
        }
        #pragma unroll
        for (int i = 0; i < 4; ++i)
            accl[kh][(lane >> 4) * 4 + i][gc] = acc[i];
        __syncthreads();   // all FMH reads done; accl complete for gating

        if (tid < 64) {                    // gating: lane -> (batch, col-pair)
            const int b = lane >> 2, jp = (lane & 3) * 2;
            float hn2[2], cn2[2];
            #pragma unroll
            for (int u = 0; u < 2; ++u) {
                const int j = jp + u;
                float pre[4];
                #pragma unroll
                for (int g = 0; g < 4; ++g) {
                    const int c = g * 8 + j;
                    pre[g] = accl[0][b][c] + accl[1][b][c] + bias_l[c];
                }
                const float ig = 1.f / (1.f + __expf(-pre[0]));
                const float fg = 1.f / (1.f + __expf(-pre[1]));
                const float gg = tanhf(pre[2]);
                const float og = 1.f / (1.f + __expf(-pre[3]));
                const float cp = (t == 0) ? 0.f : c_st[b][j];
                const float cn = fg * cp + ig * gg;
                const float hn = og * tanhf(cn);
                c_st[b][j] = cn;
                hn2[u] = hn; cn2[u] = cn;
            }
            const unsigned pack = (unsigned)(unsigned short)f2bf(hn2[0])
                                | ((unsigned)(unsigned short)f2bf(hn2[1]) << 16);
            __hip_atomic_store(
                &g_hws[(t & 1) * (BB * HW2) + (bb0 + b) * HW2 + ((hc0 + jp) >> 1)],
                pack, __ATOMIC_RELAXED, __HIP_MEMORY_SCOPE_AGENT);
            // wave-level ack: all lanes' h-stores reached the coherence point
            asm volatile("s_waitcnt vmcnt(0)" ::: "memory");
            if (lane == 0 && t < SS - 1)
                __hip_atomic_store(&g_flag[(gid * GBLK + lid) << 4], (unsigned)(t + 1),
                                   __ATOMIC_RELAXED, __HIP_MEMORY_SCOPE_AGENT);
            // fp32 outputs off the critical path, after the flag
            const size_t o = ((size_t)(bb0 + b) * SS + t) * HH + hc0 + jp;
            *(float2*)&p.out_h[o] = make_float2(hn2[0], hn2[1]);
            *(float2*)&p.out_c[o] = make_float2(cn2[0], cn2[1]);
        }
        if (t == SS - 1) break;
        // ---- hide flag propagation: x-part of t+1 (h-independent) ----
        acc = (f32x4){0.f, 0.f, 0.f, 0.f};
        acc = xpart(t + 1, acc);
    }

    // ---- end-of-run: last block resets flags for the next graph replay ----
    __syncthreads();
    if (tid == 0) {
        unsigned v = __hip_atomic_fetch_add(&g_done, 1u, __ATOMIC_RELAXED,
                                            __HIP_MEMORY_SCOPE_AGENT) + 1;
        if (v == NBLK) {
            for (int i = 0; i < NBLK; ++i)
                __hip_atomic_store(&g_flag[i << 4], 0u, __ATOMIC_RELAXED,
                                   __HIP_MEMORY_SCOPE_AGENT);
            __hip_atomic_store(&g_done, 0u, __ATOMIC_RELAXED,
                               __HIP_MEMORY_SCOPE_AGENT);
        }
    }
}

extern "C" void kernel_launch(void* const* d_in, const int* in_sizes, int n_in,
                              void* d_out, int out_size, void* d_ws, size_t ws_size,
                              hipStream_t stream) {
    (void)in_sizes; (void)n_in; (void)d_ws; (void)ws_size; (void)out_size;
    Params p;
    p.x = (const float*)d_in[0];
    for (int g = 0; g < 4; ++g) {
        p.Wi[g]   = (const float*)d_in[1 + g];
        p.Wh[g]   = (const float*)d_in[5 + g];
        p.bias[g] = (const float*)d_in[9 + g];
    }
    p.out_h = (float*)d_out;
    p.out_c = p.out_h + (size_t)BB * SS * HH;
    lstm_mfma<<<dim3(NBLK), dim3(256), 0, stream>>>(p);
}